// Round 1
// baseline (84.438 us; speedup 1.0000x reference)
//
#include <hip/hip_runtime.h>

// 4-qubit state-vector simulator, one thread per batch element.
// State: 16 complex amplitudes in registers (re[16], im[16]).
// Feature map H+RZ collapses to a tensor product of per-wire phase factors.
// CNOTs are compile-time index permutations (register renames, 0 ALU ops).
// RY gates are real Givens rotations applied to re/im independently.

__global__ __launch_bounds__(256) void qsim_kernel(
    const float* __restrict__ inputs,   // (B,4) f32
    const float* __restrict__ params,   // (2,4) f32, batch-uniform
    float* __restrict__ out,            // (B,4) f32
    int B)
{
    int b = blockIdx.x * blockDim.x + threadIdx.x;
    if (b >= B) return;

    const float4 x4 = reinterpret_cast<const float4*>(inputs)[b];

    // e^{+i x_w/2} = (cw, sw); bit=0 of wire w gets the conjugate.
    float cw[4], sw[4];
    __sincosf(0.5f * x4.x, &sw[0], &cw[0]);
    __sincosf(0.5f * x4.y, &sw[1], &cw[1]);
    __sincosf(0.5f * x4.z, &sw[2], &cw[2]);
    __sincosf(0.5f * x4.w, &sw[3], &cw[3]);

    // amp_k = 0.25 * prod_w phase_w(bit_w(k)), bit_w(k) = (k >> (3-w)) & 1
    float re[16], im[16];

    // wire 3 (lsb, stride 1)
    re[0] = 0.25f * cw[3]; im[0] = -0.25f * sw[3];
    re[1] = 0.25f * cw[3]; im[1] =  0.25f * sw[3];
    // wire 2 (stride 2)
    {
        const float c = cw[2], s = sw[2];
        #pragma unroll
        for (int j = 0; j < 2; ++j) {
            const float ar = re[j], ai = im[j];
            re[j+2] = ar*c - ai*s;  im[j+2] = ar*s + ai*c;   // bit=1: *(c+is)
            re[j]   = ar*c + ai*s;  im[j]   = ai*c - ar*s;   // bit=0: *(c-is)
        }
    }
    // wire 1 (stride 4)
    {
        const float c = cw[1], s = sw[1];
        #pragma unroll
        for (int j = 0; j < 4; ++j) {
            const float ar = re[j], ai = im[j];
            re[j+4] = ar*c - ai*s;  im[j+4] = ar*s + ai*c;
            re[j]   = ar*c + ai*s;  im[j]   = ai*c - ar*s;
        }
    }
    // wire 0 (msb, stride 8)
    {
        const float c = cw[0], s = sw[0];
        #pragma unroll
        for (int j = 0; j < 8; ++j) {
            const float ar = re[j], ai = im[j];
            re[j+8] = ar*c - ai*s;  im[j+8] = ar*s + ai*c;
            re[j]   = ar*c + ai*s;  im[j]   = ai*c - ar*s;
        }
    }

    // CNOT(control mask cm, target mask tm): swap amp[j] <-> amp[j|tm]
    // for j with control bit set, target bit clear. Pure register perm.
    auto cnot = [&](int cm, int tm) {
        #pragma unroll
        for (int j = 0; j < 16; ++j) {
            if ((j & cm) && !(j & tm)) {
                const int k = j | tm;
                float tr = re[j]; re[j] = re[k]; re[k] = tr;
                float ti = im[j]; im[j] = im[k]; im[k] = ti;
            }
        }
    };

    // RY(theta) on wire with mask m: [[c,-s],[s,c]] on (amp[j], amp[j|m])
    auto ry = [&](int m, float c, float s) {
        #pragma unroll
        for (int j = 0; j < 16; ++j) {
            if (!(j & m)) {
                const int k = j | m;
                const float a0r = re[j], a0i = im[j];
                const float a1r = re[k], a1i = im[k];
                re[j] = c*a0r - s*a1r;  im[j] = c*a0i - s*a1i;
                re[k] = s*a0r + c*a1r;  im[k] = s*a0i + c*a1i;
            }
        }
    };

    // feature-map CNOT chain: (0,1),(1,2),(2,3); wire w -> mask 1<<(3-w)
    cnot(8, 4); cnot(4, 2); cnot(2, 1);

    // variational layers
    #pragma unroll
    for (int l = 0; l < 2; ++l) {
        float cp[4], sp[4];
        #pragma unroll
        for (int w = 0; w < 4; ++w)
            __sincosf(0.5f * params[l*4 + w], &sp[w], &cp[w]);
        ry(8, cp[0], sp[0]);
        ry(4, cp[1], sp[1]);
        ry(2, cp[2], sp[2]);
        ry(1, cp[3], sp[3]);
        cnot(8, 4); cnot(4, 2); cnot(2, 1); cnot(1, 8);
    }

    // probs + PauliZ expvals via partial Walsh butterfly
    float p[16];
    #pragma unroll
    for (int k = 0; k < 16; ++k) p[k] = re[k]*re[k] + im[k]*im[k];

    float t[8];
    float o3 = 0.f;
    #pragma unroll
    for (int j = 0; j < 8; ++j) {
        t[j] = p[2*j] + p[2*j+1];
        o3  += p[2*j] - p[2*j+1];
    }
    float u[4];
    float o2 = 0.f;
    #pragma unroll
    for (int j = 0; j < 4; ++j) {
        u[j] = t[2*j] + t[2*j+1];
        o2  += t[2*j] - t[2*j+1];
    }
    const float o1 = (u[0] - u[1]) + (u[2] - u[3]);
    const float o0 = (u[0] + u[1]) - (u[2] + u[3]);

    reinterpret_cast<float4*>(out)[b] = make_float4(o0, o1, o2, o3);
}

extern "C" void kernel_launch(void* const* d_in, const int* in_sizes, int n_in,
                              void* d_out, int out_size, void* d_ws, size_t ws_size,
                              hipStream_t stream) {
    const float* inputs = (const float*)d_in[0];
    const float* params = (const float*)d_in[1];
    float* out = (float*)d_out;
    const int B = in_sizes[0] / 4;
    const int threads = 256;
    const int blocks = (B + threads - 1) / threads;
    qsim_kernel<<<blocks, threads, 0, stream>>>(inputs, params, out, B);
}

// Round 2
// 79.752 us; speedup vs baseline: 1.0588x; 1.0588x over previous
//
#include <hip/hip_runtime.h>

// 4-qubit state-vector simulator, one thread per batch element.
// State: 16 complex amps as v2f (re,im) pairs -> every gate op is identical
// on both halves, so the backend can select v_pk_fma_f32 / v_pk_mul_f32
// (VOP3P packed fp32, 2x throughput vs scalar VALU on CDNA).
// CNOTs are compile-time register permutations (0 ALU).

typedef float v2f __attribute__((ext_vector_type(2)));

__global__ __launch_bounds__(256) void qsim_kernel(
    const float* __restrict__ inputs,   // (B,4) f32
    const float* __restrict__ params,   // (2,4) f32, batch-uniform
    float* __restrict__ out,            // (B,4) f32
    int B)
{
    int b = blockIdx.x * blockDim.x + threadIdx.x;
    if (b >= B) return;

    const float4 x4 = reinterpret_cast<const float4*>(inputs)[b];

    // e^{+i x_w/2} = (cw, sw)
    float cw[4], sw[4];
    __sincosf(0.5f * x4.x, &sw[0], &cw[0]);
    __sincosf(0.5f * x4.y, &sw[1], &cw[1]);
    __sincosf(0.5f * x4.z, &sw[2], &cw[2]);
    __sincosf(0.5f * x4.w, &sw[3], &cw[3]);

    // amp_k = 0.25 * prod_w phase_w(bit_w(k)); bit=0 gets conjugate.
    v2f a[16];
    a[0] = (v2f){0.25f * cw[3], -0.25f * sw[3]};
    a[1] = (v2f){0.25f * cw[3],  0.25f * sw[3]};

    // expand wires 2,1,0 (strides 2,4,8): multiply by (c -+ i s)
    // bit0: cv - sp, bit1: cv + sp, with sp = s * (-v.y, v.x)
    #pragma unroll
    for (int lvl = 0; lvl < 3; ++lvl) {
        const int w = 2 - lvl;           // wire index 2,1,0
        const int st = 2 << lvl;         // stride 2,4,8
        const float c = cw[w], s = sw[w];
        #pragma unroll
        for (int j = 0; j < 8; ++j) {
            if (j < st) {
                const v2f v  = a[j];
                const v2f cv = v * c;
                const v2f sp = (v2f){-v.y, v.x} * s;  // op_sel+neg folds into pk_mul
                a[j]      = cv - sp;
                a[j + st] = cv + sp;
            }
        }
    }

    // CNOT(control mask cm, target mask tm): register permutation
    auto cnot = [&](int cm, int tm) {
        #pragma unroll
        for (int j = 0; j < 16; ++j) {
            if ((j & cm) && !(j & tm)) {
                const int k = j | tm;
                v2f tmp = a[j]; a[j] = a[k]; a[k] = tmp;
            }
        }
    };

    // RY on wire mask m: [[c,-s],[s,c]] on (a[j], a[j|m]) -- same rotation
    // for re and im halves -> 2 pk-instrs per output.
    auto ry = [&](int m, float c, float s) {
        #pragma unroll
        for (int j = 0; j < 16; ++j) {
            if (!(j & m)) {
                const int k = j | m;
                const v2f a0 = a[j], a1 = a[k];
                a[j] = a0 * c - a1 * s;
                a[k] = a0 * s + a1 * c;
            }
        }
    };

    // feature-map CNOT chain (0,1),(1,2),(2,3); wire w -> mask 1<<(3-w)
    cnot(8, 4); cnot(4, 2); cnot(2, 1);

    #pragma unroll
    for (int l = 0; l < 2; ++l) {
        float cp[4], sp[4];
        #pragma unroll
        for (int w = 0; w < 4; ++w)
            __sincosf(0.5f * params[l * 4 + w], &sp[w], &cp[w]);
        ry(8, cp[0], sp[0]);
        ry(4, cp[1], sp[1]);
        ry(2, cp[2], sp[2]);
        ry(1, cp[3], sp[3]);
        cnot(8, 4); cnot(4, 2); cnot(2, 1); cnot(1, 8);
    }

    // probs + PauliZ expvals: keep (re^2, im^2) packed through the whole
    // Walsh butterfly; horizontal .x+.y only at the end.
    v2f q[16];
    #pragma unroll
    for (int k = 0; k < 16; ++k) q[k] = a[k] * a[k];

    v2f t[8], o3v = (v2f){0.f, 0.f};
    #pragma unroll
    for (int j = 0; j < 8; ++j) {
        t[j] = q[2*j] + q[2*j+1];
        o3v += q[2*j] - q[2*j+1];
    }
    v2f u[4], o2v = (v2f){0.f, 0.f};
    #pragma unroll
    for (int j = 0; j < 4; ++j) {
        u[j] = t[2*j] + t[2*j+1];
        o2v += t[2*j] - t[2*j+1];
    }
    const v2f o1v = (u[0] - u[1]) + (u[2] - u[3]);
    const v2f o0v = (u[0] + u[1]) - (u[2] + u[3]);

    reinterpret_cast<float4*>(out)[b] =
        make_float4(o0v.x + o0v.y, o1v.x + o1v.y, o2v.x + o2v.y, o3v.x + o3v.y);
}

extern "C" void kernel_launch(void* const* d_in, const int* in_sizes, int n_in,
                              void* d_out, int out_size, void* d_ws, size_t ws_size,
                              hipStream_t stream) {
    const float* inputs = (const float*)d_in[0];
    const float* params = (const float*)d_in[1];
    float* out = (float*)d_out;
    const int B = in_sizes[0] / 4;
    const int threads = 256;
    const int blocks = (B + threads - 1) / threads;
    qsim_kernel<<<blocks, threads, 0, stream>>>(inputs, params, out, B);
}

// Round 3
// 75.991 us; speedup vs baseline: 1.1112x; 1.0495x over previous
//
#include <hip/hip_runtime.h>

// out_w(x) = (1/16) * sum_{m!=m'} G_w[m,m'] * cos(eps(m,m') . x)
//   G_w = V^T D_w V  (V = batch-uniform real variational circuit incl. CNOT chains)
//   eps_u = bit_u(m)-bit_u(m') in {-1,0,1}; diagonal drops out (trace(D_w)=0, V orthogonal).
// Prep kernel (1 block): simulate V's 16 columns, form G_w, group by canonical eps
// (first nonzero digit = +1; 40 classes) into an 81-slot x float4 table in d_ws.
// Main kernel: 4 sincos + canonical product tree (36 complex muls) + 80 pk_fma.

typedef float v2f __attribute__((ext_vector_type(2)));

__global__ void qprep_kernel(const float* __restrict__ params, float* __restrict__ tab) {
    __shared__ float V[16][16];   // V[row][col]
    __shared__ float4 T[81];
    const int tid = threadIdx.x;
    if (tid < 81) T[tid] = make_float4(0.f, 0.f, 0.f, 0.f);
    if (tid < 16) {
        float col[16];
        #pragma unroll
        for (int j = 0; j < 16; ++j) col[j] = (j == tid) ? 1.f : 0.f;
        auto cnot = [&](int cm, int tm) {
            #pragma unroll
            for (int j = 0; j < 16; ++j)
                if ((j & cm) && !(j & tm)) { int k = j | tm; float t0 = col[j]; col[j] = col[k]; col[k] = t0; }
        };
        auto ry = [&](int m, float c, float s) {
            #pragma unroll
            for (int j = 0; j < 16; ++j)
                if (!(j & m)) { int k = j | m; float a0 = col[j], a1 = col[k]; col[j] = c*a0 - s*a1; col[k] = s*a0 + c*a1; }
        };
        cnot(8, 4); cnot(4, 2); cnot(2, 1);          // feature-map CNOT chain
        #pragma unroll
        for (int l = 0; l < 2; ++l) {
            float cp[4], sp[4];
            #pragma unroll
            for (int w = 0; w < 4; ++w) __sincosf(0.5f * params[l*4 + w], &sp[w], &cp[w]);
            ry(8, cp[0], sp[0]); ry(4, cp[1], sp[1]); ry(2, cp[2], sp[2]); ry(1, cp[3], sp[3]);
            cnot(8, 4); cnot(4, 2); cnot(2, 1); cnot(1, 8);
        }
        #pragma unroll
        for (int j = 0; j < 16; ++j) V[j][tid] = col[j];
    }
    __syncthreads();
    for (int it = tid; it < 1024; it += 256) {
        const int w = it >> 8, m = (it >> 4) & 15, mp = it & 15;
        if (m == mp) continue;
        int t = 0; int first = 1;
        #pragma unroll
        for (int u = 0; u < 4; ++u) {
            const int d = ((m >> (3 - u)) & 1) - ((mp >> (3 - u)) & 1) + 1;
            t = t * 3 + d;
            if (first == 1 && d != 1) first = d;
        }
        if (first != 2) continue;     // keep canonical ordering only (covers each unordered pair once)
        float g = 0.f;
        #pragma unroll
        for (int k = 0; k < 16; ++k) {
            const float sgn = ((k >> (3 - w)) & 1) ? -1.f : 1.f;
            g += sgn * V[k][m] * V[k][mp];
        }
        atomicAdd(((float*)&T[t]) + w, 0.125f * g);   // 2/16 weight folded in
    }
    __syncthreads();
    if (tid < 81) reinterpret_cast<float4*>(tab)[tid] = T[tid];
}

__device__ __forceinline__ v2f cm2(v2f a, v2f bv, v2f br) { return a.x * bv + a.y * br; }

__global__ __launch_bounds__(256) void qmain_kernel(
    const float* __restrict__ inputs,   // (B,4)
    const float4* __restrict__ tab,     // 81 x float4 coefficients (uniform)
    float* __restrict__ out,            // (B,4)
    int B)
{
    const int b = blockIdx.x * blockDim.x + threadIdx.x;
    if (b >= B) return;
    const float4 x = reinterpret_cast<const float4*>(inputs)[b];

    v2f e[4], r[4], ec[4], rc[4];
    {
        float cc, ss;
        __sincosf(x.x, &ss, &cc); e[0] = (v2f){cc, ss};
        __sincosf(x.y, &ss, &cc); e[1] = (v2f){cc, ss};
        __sincosf(x.z, &ss, &cc); e[2] = (v2f){cc, ss};
        __sincosf(x.w, &ss, &cc); e[3] = (v2f){cc, ss};
    }
    #pragma unroll
    for (int u = 0; u < 4; ++u) {
        r[u]  = (v2f){-e[u].y, e[u].x};   // for z*e:      z.x*e + z.y*r
        ec[u] = (v2f){ e[u].x, -e[u].y};  // for z*conj(e): z.x*ec + z.y*rc
        rc[u] = (v2f){ e[u].y,  e[u].x};
    }

    // canonical prefix products over wires 0..2 (digit d = eps+1, msd first)
    v2f P2[9], P3[27];
    #pragma unroll
    for (int t = 0; t < 9; ++t) {
        const int d0 = t / 3, d1 = t % 3;
        if (d0 == 0 || (d0 == 1 && d1 == 0)) continue;
        if (d0 == 1) P2[t] = (d1 == 1) ? (v2f){1.f, 0.f} : e[1];
        else         P2[t] = (d1 == 1) ? e[0]
                           : (d1 == 2) ? cm2(e[0], e[1], r[1])
                                       : cm2(e[0], ec[1], rc[1]);
    }
    #pragma unroll
    for (int t = 0; t < 27; ++t) {
        const int d0 = t / 9, d1 = (t / 3) % 3, d2 = t % 3;
        const bool ones01 = (d0 == 1 && d1 == 1);
        if (d0 == 0 || (d0 == 1 && d1 == 0) || (ones01 && d2 == 0)) continue;
        if (ones01) P3[t] = (d2 == 1) ? (v2f){1.f, 0.f} : e[2];
        else {
            const int tp = t / 3;
            P3[t] = (d2 == 1) ? P2[tp]
                  : (d2 == 2) ? cm2(P2[tp], e[2], r[2])
                              : cm2(P2[tp], ec[2], rc[2]);
        }
    }

    v2f o01 = (v2f){0.f, 0.f}, o23 = (v2f){0.f, 0.f};
    #pragma unroll
    for (int t = 0; t < 81; ++t) {
        const int d0 = t / 27, d1 = (t / 9) % 3, d2 = (t / 3) % 3, d3 = t % 3;
        const int first = (d0 != 1) ? d0 : (d1 != 1) ? d1 : (d2 != 1) ? d2 : (d3 != 1) ? d3 : 1;
        if (first != 2) continue;                      // canonical eps only (40 slots)
        const bool ones012 = (d0 == 1 && d1 == 1 && d2 == 1);
        float cv;
        if (ones012) cv = e[3].x;                      // only d3==2 reaches here
        else {
            const int tp = t / 3;
            if (d3 == 1)      cv = P3[tp].x;
            else if (d3 == 2) cv = P3[tp].x * e[3].x - P3[tp].y * e[3].y;
            else              cv = P3[tp].x * e[3].x + P3[tp].y * e[3].y;
        }
        const float4 cf = tab[t];                      // uniform addr -> scalar/L1 broadcast
        o01 += cv * (v2f){cf.x, cf.y};
        o23 += cv * (v2f){cf.z, cf.w};
    }

    reinterpret_cast<float4*>(out)[b] = make_float4(o01.x, o01.y, o23.x, o23.y);
}

extern "C" void kernel_launch(void* const* d_in, const int* in_sizes, int n_in,
                              void* d_out, int out_size, void* d_ws, size_t ws_size,
                              hipStream_t stream) {
    const float* inputs = (const float*)d_in[0];
    const float* params = (const float*)d_in[1];
    float* out = (float*)d_out;
    float* tab = (float*)d_ws;                 // 81*4 floats = 1296 B
    const int B = in_sizes[0] / 4;

    qprep_kernel<<<1, 256, 0, stream>>>(params, tab);
    const int threads = 256;
    const int blocks = (B + threads - 1) / threads;
    qmain_kernel<<<blocks, threads, 0, stream>>>(inputs, (const float4*)tab, out, B);
}